// Round 7
// baseline (72.477 us; speedup 1.0000x reference)
//
#include <hip/hip_runtime.h>

#define BB 8
#define NN 256
#define DD 128
#define SW 257  // W_msg row stride (2D+1)
#define SU 256  // W_upd row stride (2D)
#define EPSV 1e-5f

__device__ __forceinline__ float wave_reduce_add(float v) {
#pragma unroll
  for (int off = 32; off > 0; off >>= 1) v += __shfl_xor(v, off, 64);
  return v;
}

// ---------------- K1: centered u,s + per-row LN scalars + wtilde -----------
// 256 threads: half 0 -> u (Wt), half 1 -> s (Ws). 2 rows/block (4 waves/SIMD).
__global__ __launch_bounds__(256) void k_proj(
    const float* __restrict__ h, const float* __restrict__ Wm,
    const float* __restrict__ bmsg,
    float* __restrict__ u, float* __restrict__ s,
    float* __restrict__ rowA, float* __restrict__ rowB,
    float* __restrict__ rowD2, float* __restrict__ rowE2,
    float* __restrict__ wtilv) {
  const int blk = blockIdx.x;            // 1024: 128 per batch, 2 rows each
  const int b = blk >> 7;
  const int r0 = (blk & 127) * 2;
  const int tid = threadIdx.x;
  const int half = tid >> 7, e = tid & 127;
  const int wv = tid >> 6, lane = tid & 63;

  __shared__ float hs[2][DD];
  __shared__ float pS[4][2], pw[2], pQ[4][2], pD[4][2];

  const float* hb = h + (size_t)(b * NN + r0) * DD;
  if (tid < DD) {
#pragma unroll
    for (int r = 0; r < 2; ++r) hs[r][e] = hb[r * DD + e];
  }
  __syncthreads();

  float acc[2];
  const float bm = (half == 0) ? bmsg[e] : 0.f;   // fold b_msg into u
#pragma unroll
  for (int r = 0; r < 2; ++r) acc[r] = bm;

  const float* wr = Wm + (size_t)e * SW + half * DD;
#pragma unroll 8
  for (int k = 0; k < DD; k += 4) {
    const float4 w4 = *(const float4*)(wr + k);
#pragma unroll
    for (int r = 0; r < 2; ++r) {
      const float4 hv = *(const float4*)(&hs[r][k]);
      acc[r] = fmaf(hv.x, w4.x, acc[r]);
      acc[r] = fmaf(hv.y, w4.y, acc[r]);
      acc[r] = fmaf(hv.z, w4.z, acc[r]);
      acc[r] = fmaf(hv.w, w4.w, acc[r]);
    }
  }

  const float we = Wm[(size_t)e * SW + 2 * DD];   // wJ[e]
#pragma unroll
  for (int r = 0; r < 2; ++r) {
    const float sm = wave_reduce_add(acc[r]);
    if (lane == 0) pS[wv][r] = sm;
  }
  {
    const float sw = wave_reduce_add(we);
    if (lane == 0 && wv < 2) pw[wv] = sw;         // half-0 waves cover e=0..127
  }
  __syncthreads();

  const int b2 = half * 2;
  const float muw = (pw[0] + pw[1]) * (1.f / DD);
  const float wtil = we - muw;
  float c[2];
#pragma unroll
  for (int r = 0; r < 2; ++r)
    c[r] = acc[r] - (pS[b2][r] + pS[b2 + 1][r]) * (1.f / DD);

  float* outp = (half == 0 ? u : s) + (size_t)(b * NN + r0) * DD;
#pragma unroll
  for (int r = 0; r < 2; ++r) outp[r * DD + e] = c[r];
  if (blk == 0 && half == 0) wtilv[e] = wtil;     // shared by all k_msg blocks

#pragma unroll
  for (int r = 0; r < 2; ++r) {
    const float q = wave_reduce_add(c[r] * c[r]);
    const float dd = wave_reduce_add(c[r] * wtil);
    if (lane == 0) { pQ[wv][r] = q; pD[wv][r] = dd; }
  }
  __syncthreads();
  if (tid < 2) {
    const int row = b * NN + r0 + tid;
    rowA[row]  = pQ[0][tid] + pQ[1][tid];
    rowD2[row] = 2.f * (pD[0][tid] + pD[1][tid]);
    rowB[row]  = pQ[2][tid] + pQ[3][tid];
    rowE2[row] = 2.f * (pD[2][tid] + pD[3][tid]);
  }
}

// ---------------- K2: P = A_i + B_j + 2*dot(u~_i, s~_j)  (32x32 tiles) -----
__global__ __launch_bounds__(256) void k_cross(
    const float* __restrict__ u, const float* __restrict__ s,
    const float* __restrict__ rowA, const float* __restrict__ rowB,
    float* __restrict__ Gp) {
  const int bid = blockIdx.x;            // 512: b*64 + tile
  const int b = bid >> 6;
  const int t = bid & 63;
  const int r0 = (t >> 3) * 32, c0 = (t & 7) * 32;
  const int tid = threadIdx.x;
  const int ty = tid >> 4, tx = tid & 15;

  __shared__ float Us[32][132], Ss[32][132];
  const float* ub = u + (size_t)(b * NN + r0) * DD;
  const float* sb = s + (size_t)(b * NN + c0) * DD;
  {
    const int row = tid >> 5, col = (tid & 31) * 4;
#pragma unroll
    for (int rr = 0; rr < 4; ++rr) {
      const float4 uv = *(const float4*)(ub + (size_t)(row + rr * 8) * DD + col);
      const float4 sv = *(const float4*)(sb + (size_t)(row + rr * 8) * DD + col);
      *(float4*)(&Us[row + rr * 8][col]) = uv;
      *(float4*)(&Ss[row + rr * 8][col]) = sv;
    }
  }
  __syncthreads();

  float a00 = 0, a01 = 0, a10 = 0, a11 = 0;
  for (int k = 0; k < DD; k += 4) {
    const float4 A0 = *(const float4*)(&Us[ty][k]);
    const float4 A1 = *(const float4*)(&Us[ty + 16][k]);
    const float4 B0 = *(const float4*)(&Ss[tx][k]);
    const float4 B1 = *(const float4*)(&Ss[tx + 16][k]);
    a00 = fmaf(A0.x, B0.x, a00); a00 = fmaf(A0.y, B0.y, a00);
    a00 = fmaf(A0.z, B0.z, a00); a00 = fmaf(A0.w, B0.w, a00);
    a01 = fmaf(A0.x, B1.x, a01); a01 = fmaf(A0.y, B1.y, a01);
    a01 = fmaf(A0.z, B1.z, a01); a01 = fmaf(A0.w, B1.w, a01);
    a10 = fmaf(A1.x, B0.x, a10); a10 = fmaf(A1.y, B0.y, a10);
    a10 = fmaf(A1.z, B0.z, a10); a10 = fmaf(A1.w, B0.w, a10);
    a11 = fmaf(A1.x, B1.x, a11); a11 = fmaf(A1.y, B1.y, a11);
    a11 = fmaf(A1.z, B1.z, a11); a11 = fmaf(A1.w, B1.w, a11);
  }
  const float Ar0 = rowA[b * NN + r0 + ty];
  const float Ar1 = rowA[b * NN + r0 + ty + 16];
  const float Bc0 = rowB[b * NN + c0 + tx];
  const float Bc1 = rowB[b * NN + c0 + tx + 16];
  float* gp = Gp + ((size_t)(b * NN + r0 + ty)) * NN + c0;
  gp[tx]                = Ar0 + Bc0 + 2.f * a00;
  gp[tx + 16]           = Ar0 + Bc1 + 2.f * a01;
  gp[16 * NN + tx]      = Ar1 + Bc0 + 2.f * a10;
  gp[16 * NN + tx + 16] = Ar1 + Bc1 + 2.f * a11;
}

// ---------------- K3: fused message LN+SiLU+aggregate (branchless loop) ----
__global__ __launch_bounds__(256) void k_msg(
    const float* __restrict__ u, const float* __restrict__ s,
    const float* __restrict__ Gp, const float* __restrict__ rowD2,
    const float* __restrict__ rowE2, const float* __restrict__ adj,
    const float* __restrict__ wtilv, const float* __restrict__ g,
    const float* __restrict__ be, float* __restrict__ agg) {
  const int blk = blockIdx.x;            // 2048 = b*256 + i
  const int b = blk >> 8, i = blk & 255;
  const int tid = threadIdx.x, lane = tid & 63, wv = tid >> 6;

  __shared__ float4 s_pak[NN];           // {adj, P, E2, -}
  __shared__ float sacc[4][DD];

  s_pak[tid] = make_float4(adj[(size_t)blk * NN + tid],
                           Gp[(size_t)blk * NN + tid],
                           rowE2[b * NN + tid], 0.f);

  const float2 uu  = *(const float2*)(u + (size_t)blk * DD + 2 * lane);
  const float2 wt2 = *(const float2*)(wtilv + 2 * lane);
  const float2 g2  = *(const float2*)(g + 2 * lane);
  const float2 be2 = *(const float2*)(be + 2 * lane);
  const float C = wave_reduce_add(fmaf(wt2.x, wt2.x, wt2.y * wt2.y));
  const float D2i = rowD2[blk];
  __syncthreads();

  float acc0 = 0.f, acc1 = 0.f;
  const float* srow = s + (size_t)b * NN * DD + 2 * lane;
  // Branchless: accumulate ALL j (incl. j==i); subtract diagonal after.
#pragma unroll 4
  for (int j = wv; j < NN; j += 4) {
    const float4 pk = s_pak[j];
    const float2 ss = *(const float2*)(srow + (size_t)j * DD);
    const float aJ = pk.x;
    const float q = fmaf(aJ, fmaf(aJ, C, D2i + pk.z), pk.y);
    const float rs = __builtin_amdgcn_rsqf(fmaf(q, 1.f / DD, EPSV));
    const float x0 = fmaf(aJ, wt2.x, uu.x + ss.x);
    const float x1 = fmaf(aJ, wt2.y, uu.y + ss.y);
    const float y0 = fmaf(x0 * rs, g2.x, be2.x);
    const float y1 = fmaf(x1 * rs, g2.y, be2.y);
    acc0 = fmaf(y0, __builtin_amdgcn_rcpf(1.f + __expf(-y0)), acc0);
    acc1 = fmaf(y1, __builtin_amdgcn_rcpf(1.f + __expf(-y1)), acc1);
  }
  if (wv == (i & 3)) {                   // wave that owned j==i: subtract it
    const float4 pk = s_pak[i];
    const float2 ss = *(const float2*)(srow + (size_t)i * DD);
    const float aJ = pk.x;
    const float q = fmaf(aJ, fmaf(aJ, C, D2i + pk.z), pk.y);
    const float rs = __builtin_amdgcn_rsqf(fmaf(q, 1.f / DD, EPSV));
    const float x0 = fmaf(aJ, wt2.x, uu.x + ss.x);
    const float x1 = fmaf(aJ, wt2.y, uu.y + ss.y);
    const float y0 = fmaf(x0 * rs, g2.x, be2.x);
    const float y1 = fmaf(x1 * rs, g2.y, be2.y);
    acc0 -= y0 * __builtin_amdgcn_rcpf(1.f + __expf(-y0));
    acc1 -= y1 * __builtin_amdgcn_rcpf(1.f + __expf(-y1));
  }
  *(float2*)(&sacc[wv][2 * lane]) = make_float2(acc0, acc1);
  __syncthreads();
  if (tid < DD) {
    agg[(size_t)blk * DD + tid] =
        sacc[0][tid] + sacc[1][tid] + sacc[2][tid] + sacc[3][tid];
  }
}

// ---------------- K4: update GEMM (split-K) + LN + SiLU + residual ---------
__global__ __launch_bounds__(256) void k_upd(
    const float* __restrict__ h, const float* __restrict__ agg,
    const float* __restrict__ Wu, const float* __restrict__ bu,
    const float* __restrict__ gu, const float* __restrict__ beu,
    float* __restrict__ out) {
  const int blk = blockIdx.x;            // 1024 blocks, 2 rows each
  const int b = blk >> 7;
  const int r0 = (blk & 127) * 2;
  const int tid = threadIdx.x;
  const int half = tid >> 7, e = tid & 127;
  const int wv = tid >> 6, lane = tid & 63;

  __shared__ float hs[2][DD], ags[2][DD], comb[2][DD];
  __shared__ float pm[2][2], pq[2][2];
  const size_t base = (size_t)(b * NN + r0) * DD;
  if (tid < DD) {
#pragma unroll
    for (int r = 0; r < 2; ++r) hs[r][e] = h[base + r * DD + e];
  } else {
#pragma unroll
    for (int r = 0; r < 2; ++r) ags[r][e] = agg[base + r * DD + e];
  }
  __syncthreads();

  float acc[2];
  const float bias = (half == 0) ? bu[e] : 0.f;
#pragma unroll
  for (int r = 0; r < 2; ++r) acc[r] = bias;

  const float* wr = Wu + (size_t)e * SU + half * DD;
  const float(*inp)[DD] = (half == 0) ? hs : ags;
#pragma unroll 8
  for (int k = 0; k < DD; k += 4) {
    const float4 w4 = *(const float4*)(wr + k);
#pragma unroll
    for (int r = 0; r < 2; ++r) {
      const float4 hv = *(const float4*)(&inp[r][k]);
      acc[r] = fmaf(hv.x, w4.x, acc[r]);
      acc[r] = fmaf(hv.y, w4.y, acc[r]);
      acc[r] = fmaf(hv.z, w4.z, acc[r]);
      acc[r] = fmaf(hv.w, w4.w, acc[r]);
    }
  }
  if (half == 1) {
#pragma unroll
    for (int r = 0; r < 2; ++r) comb[r][e] = acc[r];
  }
  __syncthreads();
  float v[2];
  if (half == 0) {
#pragma unroll
    for (int r = 0; r < 2; ++r) {
      v[r] = acc[r] + comb[r][e];
      const float sm = wave_reduce_add(v[r]);
      const float sq = wave_reduce_add(v[r] * v[r]);
      if (lane == 0) { pm[wv][r] = sm; pq[wv][r] = sq; }
    }
  }
  __syncthreads();
  if (half == 0) {
    const float ge = gu[e], bee = beu[e];
#pragma unroll
    for (int r = 0; r < 2; ++r) {
      const float mean = (pm[0][r] + pm[1][r]) * (1.f / DD);
      const float var = (pq[0][r] + pq[1][r]) * (1.f / DD) - mean * mean;
      const float rs = __builtin_amdgcn_rsqf(var + EPSV);
      const float y = fmaf((v[r] - mean) * rs, ge, bee);
      const float sg = __builtin_amdgcn_rcpf(1.f + __expf(-y));
      out[base + r * DD + e] = hs[r][e] + y * sg;
    }
  }
}

extern "C" void kernel_launch(void* const* d_in, const int* in_sizes, int n_in,
                              void* d_out, int out_size, void* d_ws, size_t ws_size,
                              hipStream_t stream) {
  const float* h    = (const float*)d_in[0];
  const float* adj  = (const float*)d_in[1];
  const float* Wm   = (const float*)d_in[2];
  const float* bmsg = (const float*)d_in[3];
  const float* gmsg = (const float*)d_in[4];
  const float* bemsg= (const float*)d_in[5];
  const float* Wu   = (const float*)d_in[6];
  const float* bupd = (const float*)d_in[7];
  const float* gupd = (const float*)d_in[8];
  const float* beupd= (const float*)d_in[9];
  float* out = (float*)d_out;

  float* ws    = (float*)d_ws;
  float* u     = ws;                        // 262144
  float* s     = u + BB * NN * DD;          // 262144
  float* aggp  = s + BB * NN * DD;          // 262144
  float* Gp    = aggp + BB * NN * DD;       // 524288
  float* rowA  = Gp + BB * NN * NN;         // 2048
  float* rowB  = rowA + BB * NN;            // 2048
  float* rowD2 = rowB + BB * NN;            // 2048
  float* rowE2 = rowD2 + BB * NN;           // 2048
  float* wtilv = rowE2 + BB * NN;           // 128

  k_proj<<<1024, 256, 0, stream>>>(h, Wm, bmsg, u, s, rowA, rowB, rowD2, rowE2, wtilv);
  k_cross<<<512, 256, 0, stream>>>(u, s, rowA, rowB, Gp);
  k_msg<<<2048, 256, 0, stream>>>(u, s, Gp, rowD2, rowE2, adj, wtilv, gmsg, bemsg, aggp);
  k_upd<<<1024, 256, 0, stream>>>(h, aggp, Wu, bupd, gupd, beupd, out);
}

// Round 9
// 66.277 us; speedup vs baseline: 1.0936x; 1.0936x over previous
//
#include <hip/hip_runtime.h>
#include <hip/hip_cooperative_groups.h>

namespace cg = cooperative_groups;

#define BB 8
#define NN 256
#define DD 128
#define SW 257  // W_msg row stride (2D+1)
#define SU 256  // W_upd row stride (2D)
#define EPSV 1e-5f
#define NBF 1024  // fused grid

__device__ __forceinline__ float wave_reduce_add(float v) {
#pragma unroll
  for (int off = 32; off > 0; off >>= 1) v += __shfl_xor(v, off, 64);
  return v;
}

// ===================== fused cooperative kernel ============================
// 1024 blocks x 256 thr (4 blocks/CU needed). Phase bodies = R6 verbatim.
// LDS: 2*32*132 floats = 33.8 KB (phase 2 is the max user).
__global__ __launch_bounds__(256, 4) void k_fused(
    const float* __restrict__ h, const float* __restrict__ adj,
    const float* __restrict__ Wm, const float* __restrict__ bmsg,
    const float* __restrict__ g, const float* __restrict__ be,
    const float* __restrict__ Wu, const float* __restrict__ bu,
    const float* __restrict__ gu, const float* __restrict__ beu,
    float* __restrict__ out,
    float* __restrict__ u, float* __restrict__ s, float* __restrict__ aggp,
    float* __restrict__ Gp, float* __restrict__ rowA, float* __restrict__ rowB,
    float* __restrict__ rowD2, float* __restrict__ rowE2,
    float* __restrict__ wtilv) {
  cg::grid_group grid = cg::this_grid();
  const int blk = blockIdx.x;
  const int tid = threadIdx.x;
  const int lane = tid & 63, wv = tid >> 6;

  __shared__ __align__(16) float smem[2 * 32 * 132];   // 33.8 KB
  __shared__ float ps_a[4][4], ps_b[4][4], ps_c[4][4], ps_w[2];

  // ===== Phase 1: proj (blocks 0..511, 4 rows each) ========================
  if (blk < 512) {
    const int b = blk >> 6, r0 = (blk & 63) * 4;
    const int half = tid >> 7, e = tid & 127;
    float (*hs)[DD] = (float (*)[DD])smem;
    const float* hb = h + (size_t)(b * NN + r0) * DD;
    if (tid < DD) {
#pragma unroll
      for (int r = 0; r < 4; ++r) hs[r][e] = hb[r * DD + e];
    }
    __syncthreads();

    float acc[4];
    const float bm = (half == 0) ? bmsg[e] : 0.f;
#pragma unroll
    for (int r = 0; r < 4; ++r) acc[r] = bm;

    const float* wr = Wm + (size_t)e * SW + half * DD;
#pragma unroll 8
    for (int k = 0; k < DD; k += 4) {
      const float4 w4 = *(const float4*)(wr + k);
#pragma unroll
      for (int r = 0; r < 4; ++r) {
        const float4 hv = *(const float4*)(&hs[r][k]);
        acc[r] = fmaf(hv.x, w4.x, acc[r]);
        acc[r] = fmaf(hv.y, w4.y, acc[r]);
        acc[r] = fmaf(hv.z, w4.z, acc[r]);
        acc[r] = fmaf(hv.w, w4.w, acc[r]);
      }
    }

    const float we = Wm[(size_t)e * SW + 2 * DD];
#pragma unroll
    for (int r = 0; r < 4; ++r) {
      const float sm = wave_reduce_add(acc[r]);
      if (lane == 0) ps_a[wv][r] = sm;
    }
    {
      const float sw = wave_reduce_add(we);
      if (lane == 0 && wv < 2) ps_w[wv] = sw;
    }
    __syncthreads();

    const int b2 = half * 2;
    const float muw = (ps_w[0] + ps_w[1]) * (1.f / DD);
    const float wtil = we - muw;
    float c[4];
#pragma unroll
    for (int r = 0; r < 4; ++r)
      c[r] = acc[r] - (ps_a[b2][r] + ps_a[b2 + 1][r]) * (1.f / DD);

    float* outp = (half == 0 ? u : s) + (size_t)(b * NN + r0) * DD;
#pragma unroll
    for (int r = 0; r < 4; ++r) outp[r * DD + e] = c[r];
    if (blk == 0 && half == 0) wtilv[e] = wtil;

#pragma unroll
    for (int r = 0; r < 4; ++r) {
      const float q = wave_reduce_add(c[r] * c[r]);
      const float dd = wave_reduce_add(c[r] * wtil);
      if (lane == 0) { ps_b[wv][r] = q; ps_c[wv][r] = dd; }
    }
    __syncthreads();
    if (tid < 4) {
      const int row = b * NN + r0 + tid;
      rowA[row]  = ps_b[0][tid] + ps_b[1][tid];
      rowD2[row] = 2.f * (ps_c[0][tid] + ps_c[1][tid]);
      rowB[row]  = ps_b[2][tid] + ps_b[3][tid];
      rowE2[row] = 2.f * (ps_c[2][tid] + ps_c[3][tid]);
    }
  }
  grid.sync();

  // ===== Phase 2: cross (blocks 0..511, 32x32 tiles) =======================
  if (blk < 512) {
    const int b = blk >> 6;
    const int t = blk & 63;
    const int r0 = (t >> 3) * 32, c0 = (t & 7) * 32;
    const int ty = tid >> 4, tx = tid & 15;
    float (*Us)[132] = (float (*)[132])smem;
    float (*Ss)[132] = (float (*)[132])(smem + 32 * 132);
    const float* ub = u + (size_t)(b * NN + r0) * DD;
    const float* sb = s + (size_t)(b * NN + c0) * DD;
    {
      const int row = tid >> 5, col = (tid & 31) * 4;
#pragma unroll
      for (int rr = 0; rr < 4; ++rr) {
        const float4 uv = *(const float4*)(ub + (size_t)(row + rr * 8) * DD + col);
        const float4 sv = *(const float4*)(sb + (size_t)(row + rr * 8) * DD + col);
        *(float4*)(&Us[row + rr * 8][col]) = uv;
        *(float4*)(&Ss[row + rr * 8][col]) = sv;
      }
    }
    __syncthreads();

    float a00 = 0, a01 = 0, a10 = 0, a11 = 0;
    for (int k = 0; k < DD; k += 4) {
      const float4 A0 = *(const float4*)(&Us[ty][k]);
      const float4 A1 = *(const float4*)(&Us[ty + 16][k]);
      const float4 B0 = *(const float4*)(&Ss[tx][k]);
      const float4 B1 = *(const float4*)(&Ss[tx + 16][k]);
      a00 = fmaf(A0.x, B0.x, a00); a00 = fmaf(A0.y, B0.y, a00);
      a00 = fmaf(A0.z, B0.z, a00); a00 = fmaf(A0.w, B0.w, a00);
      a01 = fmaf(A0.x, B1.x, a01); a01 = fmaf(A0.y, B1.y, a01);
      a01 = fmaf(A0.z, B1.z, a01); a01 = fmaf(A0.w, B1.w, a01);
      a10 = fmaf(A1.x, B0.x, a10); a10 = fmaf(A1.y, B0.y, a10);
      a10 = fmaf(A1.z, B0.z, a10); a10 = fmaf(A1.w, B0.w, a10);
      a11 = fmaf(A1.x, B1.x, a11); a11 = fmaf(A1.y, B1.y, a11);
      a11 = fmaf(A1.z, B1.z, a11); a11 = fmaf(A1.w, B1.w, a11);
    }
    const float Ar0 = rowA[b * NN + r0 + ty];
    const float Ar1 = rowA[b * NN + r0 + ty + 16];
    const float Bc0 = rowB[b * NN + c0 + tx];
    const float Bc1 = rowB[b * NN + c0 + tx + 16];
    float* gp = Gp + ((size_t)(b * NN + r0 + ty)) * NN + c0;
    gp[tx]                = Ar0 + Bc0 + 2.f * a00;
    gp[tx + 16]           = Ar0 + Bc1 + 2.f * a01;
    gp[16 * NN + tx]      = Ar1 + Bc0 + 2.f * a10;
    gp[16 * NN + tx + 16] = Ar1 + Bc1 + 2.f * a11;
  }
  grid.sync();

  // ===== Phase 3: msg (all 1024 blocks, 2 i-rows each) =====================
  {
    float4* s_pak = (float4*)smem;                     // [256] = 4 KB
    float (*sacc)[DD] = (float (*)[DD])(smem + 1024);  // [4][128]

    const float2 wt2 = *(const float2*)(wtilv + 2 * lane);
    const float2 g2  = *(const float2*)(g + 2 * lane);
    const float2 be2 = *(const float2*)(be + 2 * lane);
    const float C = wave_reduce_add(fmaf(wt2.x, wt2.x, wt2.y * wt2.y));

#pragma unroll
    for (int it = 0; it < 2; ++it) {
      const int idx = blk + it * NBF;                  // (b,i) pair index
      const int b = idx >> 8, i = idx & 255;

      s_pak[tid] = make_float4(adj[(size_t)idx * NN + tid],
                               Gp[(size_t)idx * NN + tid],
                               rowE2[b * NN + tid], 0.f);
      const float2 uu = *(const float2*)(u + (size_t)idx * DD + 2 * lane);
      const float D2i = rowD2[idx];
      __syncthreads();

      float acc0 = 0.f, acc1 = 0.f;
      const float* srow = s + (size_t)b * NN * DD + 2 * lane;
#pragma unroll 4
      for (int j = wv; j < NN; j += 4) {
        if (j == i) continue;                          // wave-uniform
        const float4 pk = s_pak[j];
        const float2 ss = *(const float2*)(srow + (size_t)j * DD);
        const float aJ = pk.x;
        const float q = fmaf(aJ, fmaf(aJ, C, D2i + pk.z), pk.y);
        const float rs = __builtin_amdgcn_rsqf(fmaf(q, 1.f / DD, EPSV));
        const float x0 = fmaf(aJ, wt2.x, uu.x + ss.x);
        const float x1 = fmaf(aJ, wt2.y, uu.y + ss.y);
        const float y0 = fmaf(x0 * rs, g2.x, be2.x);
        const float y1 = fmaf(x1 * rs, g2.y, be2.y);
        acc0 = fmaf(y0, __builtin_amdgcn_rcpf(1.f + __expf(-y0)), acc0);
        acc1 = fmaf(y1, __builtin_amdgcn_rcpf(1.f + __expf(-y1)), acc1);
      }
      *(float2*)(&sacc[wv][2 * lane]) = make_float2(acc0, acc1);
      __syncthreads();
      if (tid < DD) {
        aggp[(size_t)idx * DD + tid] =
            sacc[0][tid] + sacc[1][tid] + sacc[2][tid] + sacc[3][tid];
      }
      __syncthreads();   // protect s_pak/sacc before next iteration
    }
  }
  grid.sync();

  // ===== Phase 4: upd (blocks 0..511, 4 rows each) =========================
  if (blk < 512) {
    const int b = blk >> 6, r0 = (blk & 63) * 4;
    const int half = tid >> 7, e = tid & 127;
    float (*hs)[DD]   = (float (*)[DD])smem;
    float (*ags)[DD]  = (float (*)[DD])(smem + 512);
    float (*comb)[DD] = (float (*)[DD])(smem + 1024);
    const size_t base = (size_t)(b * NN + r0) * DD;
    if (tid < DD) {
#pragma unroll
      for (int r = 0; r < 4; ++r) hs[r][e] = h[base + r * DD + e];
    } else {
#pragma unroll
      for (int r = 0; r < 4; ++r) ags[r][e] = aggp[base + r * DD + e];
    }
    __syncthreads();

    float acc[4];
    const float bias = (half == 0) ? bu[e] : 0.f;
#pragma unroll
    for (int r = 0; r < 4; ++r) acc[r] = bias;

    const float* wr = Wu + (size_t)e * SU + half * DD;
    const float(*inp)[DD] = (half == 0) ? hs : ags;
#pragma unroll 8
    for (int k = 0; k < DD; k += 4) {
      const float4 w4 = *(const float4*)(wr + k);
#pragma unroll
      for (int r = 0; r < 4; ++r) {
        const float4 hv = *(const float4*)(&inp[r][k]);
        acc[r] = fmaf(hv.x, w4.x, acc[r]);
        acc[r] = fmaf(hv.y, w4.y, acc[r]);
        acc[r] = fmaf(hv.z, w4.z, acc[r]);
        acc[r] = fmaf(hv.w, w4.w, acc[r]);
      }
    }
    if (half == 1) {
#pragma unroll
      for (int r = 0; r < 4; ++r) comb[r][e] = acc[r];
    }
    __syncthreads();
    float v[4];
    if (half == 0) {
#pragma unroll
      for (int r = 0; r < 4; ++r) {
        v[r] = acc[r] + comb[r][e];
        const float sm = wave_reduce_add(v[r]);
        const float sq = wave_reduce_add(v[r] * v[r]);
        if (lane == 0) { ps_a[wv][r] = sm; ps_b[wv][r] = sq; }
      }
    }
    __syncthreads();
    if (half == 0) {
      const float ge = gu[e], bee = beu[e];
#pragma unroll
      for (int r = 0; r < 4; ++r) {
        const float mean = (ps_a[0][r] + ps_a[1][r]) * (1.f / DD);
        const float var = (ps_b[0][r] + ps_b[1][r]) * (1.f / DD) - mean * mean;
        const float rs = __builtin_amdgcn_rsqf(var + EPSV);
        const float y = fmaf((v[r] - mean) * rs, ge, bee);
        const float sg = __builtin_amdgcn_rcpf(1.f + __expf(-y));
        out[base + r * DD + e] = hs[r][e] + y * sg;
      }
    }
  }
}

// ===================== fallback: R6 4-kernel pipeline ======================
__global__ __launch_bounds__(256) void k_proj(
    const float* __restrict__ h, const float* __restrict__ Wm,
    const float* __restrict__ bmsg,
    float* __restrict__ u, float* __restrict__ s,
    float* __restrict__ rowA, float* __restrict__ rowB,
    float* __restrict__ rowD2, float* __restrict__ rowE2,
    float* __restrict__ wtilv) {
  const int blk = blockIdx.x;
  const int b = blk >> 6;
  const int r0 = (blk & 63) * 4;
  const int tid = threadIdx.x;
  const int half = tid >> 7, e = tid & 127;
  const int wv = tid >> 6, lane = tid & 63;

  __shared__ float hs[4][DD];
  __shared__ float pS[4][4], pw[2], pQ[4][4], pD[4][4];

  const float* hb = h + (size_t)(b * NN + r0) * DD;
  if (tid < DD) {
#pragma unroll
    for (int r = 0; r < 4; ++r) hs[r][e] = hb[r * DD + e];
  }
  __syncthreads();

  float acc[4];
  const float bm = (half == 0) ? bmsg[e] : 0.f;
#pragma unroll
  for (int r = 0; r < 4; ++r) acc[r] = bm;

  const float* wr = Wm + (size_t)e * SW + half * DD;
#pragma unroll 8
  for (int k = 0; k < DD; k += 4) {
    const float4 w4 = *(const float4*)(wr + k);
#pragma unroll
    for (int r = 0; r < 4; ++r) {
      const float4 hv = *(const float4*)(&hs[r][k]);
      acc[r] = fmaf(hv.x, w4.x, acc[r]);
      acc[r] = fmaf(hv.y, w4.y, acc[r]);
      acc[r] = fmaf(hv.z, w4.z, acc[r]);
      acc[r] = fmaf(hv.w, w4.w, acc[r]);
    }
  }

  const float we = Wm[(size_t)e * SW + 2 * DD];
#pragma unroll
  for (int r = 0; r < 4; ++r) {
    const float sm = wave_reduce_add(acc[r]);
    if (lane == 0) pS[wv][r] = sm;
  }
  {
    const float sw = wave_reduce_add(we);
    if (lane == 0 && wv < 2) pw[wv] = sw;
  }
  __syncthreads();

  const int b2 = half * 2;
  const float muw = (pw[0] + pw[1]) * (1.f / DD);
  const float wtil = we - muw;
  float c[4];
#pragma unroll
  for (int r = 0; r < 4; ++r)
    c[r] = acc[r] - (pS[b2][r] + pS[b2 + 1][r]) * (1.f / DD);

  float* outp = (half == 0 ? u : s) + (size_t)(b * NN + r0) * DD;
#pragma unroll
  for (int r = 0; r < 4; ++r) outp[r * DD + e] = c[r];
  if (blk == 0 && half == 0) wtilv[e] = wtil;

#pragma unroll
  for (int r = 0; r < 4; ++r) {
    const float q = wave_reduce_add(c[r] * c[r]);
    const float dd = wave_reduce_add(c[r] * wtil);
    if (lane == 0) { pQ[wv][r] = q; pD[wv][r] = dd; }
  }
  __syncthreads();
  if (tid < 4) {
    const int row = b * NN + r0 + tid;
    rowA[row]  = pQ[0][tid] + pQ[1][tid];
    rowD2[row] = 2.f * (pD[0][tid] + pD[1][tid]);
    rowB[row]  = pQ[2][tid] + pQ[3][tid];
    rowE2[row] = 2.f * (pD[2][tid] + pD[3][tid]);
  }
}

__global__ __launch_bounds__(256) void k_cross(
    const float* __restrict__ u, const float* __restrict__ s,
    const float* __restrict__ rowA, const float* __restrict__ rowB,
    float* __restrict__ Gp) {
  const int bid = blockIdx.x;
  const int b = bid >> 6;
  const int t = bid & 63;
  const int r0 = (t >> 3) * 32, c0 = (t & 7) * 32;
  const int tid = threadIdx.x;
  const int ty = tid >> 4, tx = tid & 15;

  __shared__ float Us[32][132], Ss[32][132];
  const float* ub = u + (size_t)(b * NN + r0) * DD;
  const float* sb = s + (size_t)(b * NN + c0) * DD;
  {
    const int row = tid >> 5, col = (tid & 31) * 4;
#pragma unroll
    for (int rr = 0; rr < 4; ++rr) {
      const float4 uv = *(const float4*)(ub + (size_t)(row + rr * 8) * DD + col);
      const float4 sv = *(const float4*)(sb + (size_t)(row + rr * 8) * DD + col);
      *(float4*)(&Us[row + rr * 8][col]) = uv;
      *(float4*)(&Ss[row + rr * 8][col]) = sv;
    }
  }
  __syncthreads();

  float a00 = 0, a01 = 0, a10 = 0, a11 = 0;
  for (int k = 0; k < DD; k += 4) {
    const float4 A0 = *(const float4*)(&Us[ty][k]);
    const float4 A1 = *(const float4*)(&Us[ty + 16][k]);
    const float4 B0 = *(const float4*)(&Ss[tx][k]);
    const float4 B1 = *(const float4*)(&Ss[tx + 16][k]);
    a00 = fmaf(A0.x, B0.x, a00); a00 = fmaf(A0.y, B0.y, a00);
    a00 = fmaf(A0.z, B0.z, a00); a00 = fmaf(A0.w, B0.w, a00);
    a01 = fmaf(A0.x, B1.x, a01); a01 = fmaf(A0.y, B1.y, a01);
    a01 = fmaf(A0.z, B1.z, a01); a01 = fmaf(A0.w, B1.w, a01);
    a10 = fmaf(A1.x, B0.x, a10); a10 = fmaf(A1.y, B0.y, a10);
    a10 = fmaf(A1.z, B0.z, a10); a10 = fmaf(A1.w, B0.w, a10);
    a11 = fmaf(A1.x, B1.x, a11); a11 = fmaf(A1.y, B1.y, a11);
    a11 = fmaf(A1.z, B1.z, a11); a11 = fmaf(A1.w, B1.w, a11);
  }
  const float Ar0 = rowA[b * NN + r0 + ty];
  const float Ar1 = rowA[b * NN + r0 + ty + 16];
  const float Bc0 = rowB[b * NN + c0 + tx];
  const float Bc1 = rowB[b * NN + c0 + tx + 16];
  float* gp = Gp + ((size_t)(b * NN + r0 + ty)) * NN + c0;
  gp[tx]                = Ar0 + Bc0 + 2.f * a00;
  gp[tx + 16]           = Ar0 + Bc1 + 2.f * a01;
  gp[16 * NN + tx]      = Ar1 + Bc0 + 2.f * a10;
  gp[16 * NN + tx + 16] = Ar1 + Bc1 + 2.f * a11;
}

__global__ __launch_bounds__(256) void k_msg(
    const float* __restrict__ u, const float* __restrict__ s,
    const float* __restrict__ Gp, const float* __restrict__ rowD2,
    const float* __restrict__ rowE2, const float* __restrict__ adj,
    const float* __restrict__ wtilv, const float* __restrict__ g,
    const float* __restrict__ be, float* __restrict__ agg) {
  const int blk = blockIdx.x;
  const int b = blk >> 8, i = blk & 255;
  const int tid = threadIdx.x, lane = tid & 63, wv = tid >> 6;

  __shared__ float4 s_pak[NN];
  __shared__ float sacc[4][DD];

  s_pak[tid] = make_float4(adj[(size_t)blk * NN + tid],
                           Gp[(size_t)blk * NN + tid],
                           rowE2[b * NN + tid], 0.f);

  const float2 uu  = *(const float2*)(u + (size_t)blk * DD + 2 * lane);
  const float2 wt2 = *(const float2*)(wtilv + 2 * lane);
  const float2 g2  = *(const float2*)(g + 2 * lane);
  const float2 be2 = *(const float2*)(be + 2 * lane);
  const float C = wave_reduce_add(fmaf(wt2.x, wt2.x, wt2.y * wt2.y));
  const float D2i = rowD2[blk];
  __syncthreads();

  float acc0 = 0.f, acc1 = 0.f;
  const float* srow = s + (size_t)b * NN * DD + 2 * lane;
#pragma unroll 4
  for (int j = wv; j < NN; j += 4) {
    if (j == i) continue;
    const float4 pk = s_pak[j];
    const float2 ss = *(const float2*)(srow + (size_t)j * DD);
    const float aJ = pk.x;
    const float q = fmaf(aJ, fmaf(aJ, C, D2i + pk.z), pk.y);
    const float rs = __builtin_amdgcn_rsqf(fmaf(q, 1.f / DD, EPSV));
    const float x0 = fmaf(aJ, wt2.x, uu.x + ss.x);
    const float x1 = fmaf(aJ, wt2.y, uu.y + ss.y);
    const float y0 = fmaf(x0 * rs, g2.x, be2.x);
    const float y1 = fmaf(x1 * rs, g2.y, be2.y);
    acc0 = fmaf(y0, __builtin_amdgcn_rcpf(1.f + __expf(-y0)), acc0);
    acc1 = fmaf(y1, __builtin_amdgcn_rcpf(1.f + __expf(-y1)), acc1);
  }
  *(float2*)(&sacc[wv][2 * lane]) = make_float2(acc0, acc1);
  __syncthreads();
  if (tid < DD) {
    agg[(size_t)blk * DD + tid] =
        sacc[0][tid] + sacc[1][tid] + sacc[2][tid] + sacc[3][tid];
  }
}

__global__ __launch_bounds__(256) void k_upd(
    const float* __restrict__ h, const float* __restrict__ agg,
    const float* __restrict__ Wu, const float* __restrict__ bu,
    const float* __restrict__ gu, const float* __restrict__ beu,
    float* __restrict__ out) {
  const int blk = blockIdx.x;
  const int b = blk >> 6;
  const int r0 = (blk & 63) * 4;
  const int tid = threadIdx.x;
  const int half = tid >> 7, e = tid & 127;
  const int wv = tid >> 6, lane = tid & 63;

  __shared__ float hs[4][DD], ags[4][DD], comb[4][DD];
  __shared__ float pm[2][4], pq[2][4];
  const size_t base = (size_t)(b * NN + r0) * DD;
  if (tid < DD) {
#pragma unroll
    for (int r = 0; r < 4; ++r) hs[r][e] = h[base + r * DD + e];
  } else {
#pragma unroll
    for (int r = 0; r < 4; ++r) ags[r][e] = agg[base + r * DD + e];
  }
  __syncthreads();

  float acc[4];
  const float bias = (half == 0) ? bu[e] : 0.f;
#pragma unroll
  for (int r = 0; r < 4; ++r) acc[r] = bias;

  const float* wr = Wu + (size_t)e * SU + half * DD;
  const float(*inp)[DD] = (half == 0) ? hs : ags;
#pragma unroll 8
  for (int k = 0; k < DD; k += 4) {
    const float4 w4 = *(const float4*)(wr + k);
#pragma unroll
    for (int r = 0; r < 4; ++r) {
      const float4 hv = *(const float4*)(&inp[r][k]);
      acc[r] = fmaf(hv.x, w4.x, acc[r]);
      acc[r] = fmaf(hv.y, w4.y, acc[r]);
      acc[r] = fmaf(hv.z, w4.z, acc[r]);
      acc[r] = fmaf(hv.w, w4.w, acc[r]);
    }
  }
  if (half == 1) {
#pragma unroll
    for (int r = 0; r < 4; ++r) comb[r][e] = acc[r];
  }
  __syncthreads();
  float v[4];
  if (half == 0) {
#pragma unroll
    for (int r = 0; r < 4; ++r) {
      v[r] = acc[r] + comb[r][e];
      const float sm = wave_reduce_add(v[r]);
      const float sq = wave_reduce_add(v[r] * v[r]);
      if (lane == 0) { pm[wv][r] = sm; pq[wv][r] = sq; }
    }
  }
  __syncthreads();
  if (half == 0) {
    const float ge = gu[e], bee = beu[e];
#pragma unroll
    for (int r = 0; r < 4; ++r) {
      const float mean = (pm[0][r] + pm[1][r]) * (1.f / DD);
      const float var = (pq[0][r] + pq[1][r]) * (1.f / DD) - mean * mean;
      const float rs = __builtin_amdgcn_rsqf(var + EPSV);
      const float y = fmaf((v[r] - mean) * rs, ge, bee);
      const float sg = __builtin_amdgcn_rcpf(1.f + __expf(-y));
      out[base + r * DD + e] = hs[r][e] + y * sg;
    }
  }
}

extern "C" void kernel_launch(void* const* d_in, const int* in_sizes, int n_in,
                              void* d_out, int out_size, void* d_ws, size_t ws_size,
                              hipStream_t stream) {
  const float* h    = (const float*)d_in[0];
  const float* adj  = (const float*)d_in[1];
  const float* Wm   = (const float*)d_in[2];
  const float* bmsg = (const float*)d_in[3];
  const float* gmsg = (const float*)d_in[4];
  const float* bemsg= (const float*)d_in[5];
  const float* Wu   = (const float*)d_in[6];
  const float* bupd = (const float*)d_in[7];
  const float* gupd = (const float*)d_in[8];
  const float* beupd= (const float*)d_in[9];
  float* out = (float*)d_out;

  float* ws    = (float*)d_ws;
  float* u     = ws;
  float* s     = u + BB * NN * DD;
  float* aggp  = s + BB * NN * DD;
  float* Gp    = aggp + BB * NN * DD;
  float* rowA  = Gp + BB * NN * NN;
  float* rowB  = rowA + BB * NN;
  float* rowD2 = rowB + BB * NN;
  float* rowE2 = rowD2 + BB * NN;
  float* wtilv = rowE2 + BB * NN;

  // Cooperative path only if the runtime admits 4 blocks/CU co-residency.
  int maxBlocksPerCU = 0;
  hipError_t qe = hipOccupancyMaxActiveBlocksPerMultiprocessor(
      &maxBlocksPerCU, (const void*)k_fused, 256, 0);
  if (qe == hipSuccess && maxBlocksPerCU >= 4) {
    void* args[] = {(void*)&h,    (void*)&adj,  (void*)&Wm,    (void*)&bmsg,
                    (void*)&gmsg, (void*)&bemsg,(void*)&Wu,    (void*)&bupd,
                    (void*)&gupd, (void*)&beupd,(void*)&out,   (void*)&u,
                    (void*)&s,    (void*)&aggp, (void*)&Gp,    (void*)&rowA,
                    (void*)&rowB, (void*)&rowD2,(void*)&rowE2, (void*)&wtilv};
    hipError_t le = hipLaunchCooperativeKernel((const void*)k_fused,
                                               dim3(NBF), dim3(256), args, 0,
                                               stream);
    if (le == hipSuccess) return;
  }

  // Fallback: R6 measured-best 4-kernel pipeline.
  k_proj<<<512, 256, 0, stream>>>(h, Wm, bmsg, u, s, rowA, rowB, rowD2, rowE2, wtilv);
  k_cross<<<512, 256, 0, stream>>>(u, s, rowA, rowB, Gp);
  k_msg<<<2048, 256, 0, stream>>>(u, s, Gp, rowD2, rowE2, adj, wtilv, gmsg, bemsg, aggp);
  k_upd<<<512, 256, 0, stream>>>(h, aggp, Wu, bupd, gupd, beupd, out);
}

// Round 10
// 56.298 us; speedup vs baseline: 1.2874x; 1.1772x over previous
//
#include <hip/hip_runtime.h>

#define BB 8
#define NN 256
#define DD 128
#define SW 257  // W_msg row stride (2D+1)
#define SU 256  // W_upd row stride (2D)
#define EPSV 1e-5f

__device__ __forceinline__ float wave_reduce_add(float v) {
#pragma unroll
  for (int off = 32; off > 0; off >>= 1) v += __shfl_xor(v, off, 64);
  return v;
}

// ---------------- K1: centered u,s + per-row LN scalars + wtilde + WuT -----
// R6 measured-best body + WuT transpose epilogue (64 floats/block).
__global__ __launch_bounds__(256) void k_proj(
    const float* __restrict__ h, const float* __restrict__ Wm,
    const float* __restrict__ bmsg, const float* __restrict__ Wu,
    float* __restrict__ u, float* __restrict__ s,
    float* __restrict__ rowA, float* __restrict__ rowB,
    float* __restrict__ rowD2, float* __restrict__ rowE2,
    float* __restrict__ wtilv, float* __restrict__ wut) {
  const int blk = blockIdx.x;            // 512: 64 per batch, 4 rows each
  const int b = blk >> 6;
  const int r0 = (blk & 63) * 4;
  const int tid = threadIdx.x;
  const int half = tid >> 7, e = tid & 127;
  const int wv = tid >> 6, lane = tid & 63;

  __shared__ float hs[4][DD];
  __shared__ float pS[4][4], pw[2], pQ[4][4], pD[4][4];

  const float* hb = h + (size_t)(b * NN + r0) * DD;
  if (tid < DD) {
#pragma unroll
    for (int r = 0; r < 4; ++r) hs[r][e] = hb[r * DD + e];
  }
  // WuT transpose: wut[d*128+e] = Wu[e*256+d]; 64 elems per block.
  if (tid >= DD && tid < DD + 64) {
    const int i = blk * 64 + (tid - DD);
    const int d = i >> 7, e2 = i & 127;
    wut[i] = Wu[(size_t)e2 * SU + d];
  }
  __syncthreads();

  float acc[4];
  const float bm = (half == 0) ? bmsg[e] : 0.f;   // fold b_msg into u
#pragma unroll
  for (int r = 0; r < 4; ++r) acc[r] = bm;

  const float* wr = Wm + (size_t)e * SW + half * DD;
#pragma unroll 8
  for (int k = 0; k < DD; k += 4) {
    const float4 w4 = *(const float4*)(wr + k);
#pragma unroll
    for (int r = 0; r < 4; ++r) {
      const float4 hv = *(const float4*)(&hs[r][k]);
      acc[r] = fmaf(hv.x, w4.x, acc[r]);
      acc[r] = fmaf(hv.y, w4.y, acc[r]);
      acc[r] = fmaf(hv.z, w4.z, acc[r]);
      acc[r] = fmaf(hv.w, w4.w, acc[r]);
    }
  }

  const float we = Wm[(size_t)e * SW + 2 * DD];   // wJ[e]
#pragma unroll
  for (int r = 0; r < 4; ++r) {
    const float sm = wave_reduce_add(acc[r]);
    if (lane == 0) pS[wv][r] = sm;
  }
  {
    const float sw = wave_reduce_add(we);
    if (lane == 0 && wv < 2) pw[wv] = sw;
  }
  __syncthreads();

  const int b2 = half * 2;
  const float muw = (pw[0] + pw[1]) * (1.f / DD);
  const float wtil = we - muw;
  float c[4];
#pragma unroll
  for (int r = 0; r < 4; ++r)
    c[r] = acc[r] - (pS[b2][r] + pS[b2 + 1][r]) * (1.f / DD);

  float* outp = (half == 0 ? u : s) + (size_t)(b * NN + r0) * DD;
#pragma unroll
  for (int r = 0; r < 4; ++r) outp[r * DD + e] = c[r];
  if (blk == 0 && half == 0) wtilv[e] = wtil;

#pragma unroll
  for (int r = 0; r < 4; ++r) {
    const float q = wave_reduce_add(c[r] * c[r]);
    const float dd = wave_reduce_add(c[r] * wtil);
    if (lane == 0) { pQ[wv][r] = q; pD[wv][r] = dd; }
  }
  __syncthreads();
  if (tid < 4) {
    const int row = b * NN + r0 + tid;
    rowA[row]  = pQ[0][tid] + pQ[1][tid];
    rowD2[row] = 2.f * (pD[0][tid] + pD[1][tid]);
    rowB[row]  = pQ[2][tid] + pQ[3][tid];
    rowE2[row] = 2.f * (pD[2][tid] + pD[3][tid]);
  }
}

// ---------------- K2: fused dots + msg LN/SiLU/aggregate + upd -------------
// 1024 blocks x 256 thr; block = (b, i-pair). s-tile staged in LDS (32 rows),
// per-tile dots give rs_ij (no per-pair cross-lane op); upd tail per row.
__global__ __launch_bounds__(256) void k_msgfused(
    const float* __restrict__ h, const float* __restrict__ u,
    const float* __restrict__ s, const float* __restrict__ adj,
    const float* __restrict__ rowA, const float* __restrict__ rowB,
    const float* __restrict__ rowD2, const float* __restrict__ rowE2,
    const float* __restrict__ wtilv, const float* __restrict__ g,
    const float* __restrict__ be, const float* __restrict__ wut,
    const float* __restrict__ bu, const float* __restrict__ gu,
    const float* __restrict__ beu, float* __restrict__ out) {
  const int blk = blockIdx.x;            // 1024 = b*128 + ip
  const int b = blk >> 7, ip = blk & 127;
  const int i0 = 2 * ip, i1 = i0 + 1;
  const int tid = threadIdx.x, lane = tid & 63, wv = tid >> 6;
  const int bNN = b * NN;

  __shared__ __align__(16) float st_[32 * 132];   // s-tile; later sacc+xsh
  __shared__ __align__(16) float upair_[2 * DD];  // u~ rows; later comb
  __shared__ __align__(16) float hrow_[2 * DD];
  __shared__ float2 pak0[32], pak1[32];           // {aJ, rs}
  __shared__ float pm[2][2], pq[2][2];

  // prologue: stage u~ rows + h rows, per-lane constants, block scalars
  {
    const int ii = tid >> 7, e = tid & 127;
    upair_[ii * DD + e] = u[(size_t)(bNN + i0 + ii) * DD + e];
    hrow_[ii * DD + e]  = h[(size_t)(bNN + i0 + ii) * DD + e];
  }
  const float2 wt2 = *(const float2*)(wtilv + 2 * lane);
  const float2 g2  = *(const float2*)(g + 2 * lane);
  const float2 be2 = *(const float2*)(be + 2 * lane);
  const float C = wave_reduce_add(fmaf(wt2.x, wt2.x, wt2.y * wt2.y));
  const float A0 = rowA[bNN + i0], A1 = rowA[bNN + i1];
  const float D20 = rowD2[bNN + i0], D21 = rowD2[bNN + i1];
  __syncthreads();
  const float2 uu0 = *(const float2*)(&upair_[2 * lane]);
  const float2 uu1 = *(const float2*)(&upair_[DD + 2 * lane]);

  float accA0 = 0.f, accA1 = 0.f, accB0 = 0.f, accB1 = 0.f;
  const float* sb = s + (size_t)bNN * DD;

  for (int tile = 0; tile < 8; ++tile) {
    const int t0 = tile * 32;
    __syncthreads();                     // st/pak safe to overwrite
    // stage s-tile: 32 rows x 128 floats, coalesced 512B per 32-lane group
    {
      const int r = tid >> 5, c4 = (tid & 31) * 4;
#pragma unroll
      for (int p = 0; p < 4; ++p) {
        const int row = p * 8 + r;
        *(float4*)(&st_[row * 132 + c4]) =
            *(const float4*)(sb + (size_t)(t0 + row) * DD + c4);
      }
    }
    __syncthreads();
    // dots for both i's + rs precompute (8 lanes per j)
    {
      const int j = tid >> 3, seg = tid & 7, k0 = seg * 16;
      float d0 = 0.f, d1 = 0.f;
#pragma unroll
      for (int k = 0; k < 16; k += 4) {
        const float4 sv = *(const float4*)(&st_[j * 132 + k0 + k]);
        const float4 u0v = *(const float4*)(&upair_[k0 + k]);
        const float4 u1v = *(const float4*)(&upair_[DD + k0 + k]);
        d0 = fmaf(sv.x, u0v.x, d0); d0 = fmaf(sv.y, u0v.y, d0);
        d0 = fmaf(sv.z, u0v.z, d0); d0 = fmaf(sv.w, u0v.w, d0);
        d1 = fmaf(sv.x, u1v.x, d1); d1 = fmaf(sv.y, u1v.y, d1);
        d1 = fmaf(sv.z, u1v.z, d1); d1 = fmaf(sv.w, u1v.w, d1);
      }
#pragma unroll
      for (int m = 1; m < 8; m <<= 1) {
        d0 += __shfl_xor(d0, m, 64);
        d1 += __shfl_xor(d1, m, 64);
      }
      if (seg == 0) {
        const int jg = t0 + j;
        const float Bj = rowB[bNN + jg], E2j = rowE2[bNN + jg];
        const float a0 = adj[(size_t)(bNN + i0) * NN + jg];
        const float a1 = adj[(size_t)(bNN + i1) * NN + jg];
        const float q0 = fmaf(a0, fmaf(a0, C, D20 + E2j), A0 + Bj + 2.f * d0);
        const float q1 = fmaf(a1, fmaf(a1, C, D21 + E2j), A1 + Bj + 2.f * d1);
        pak0[j] = make_float2(a0, __builtin_amdgcn_rsqf(fmaf(q0, 1.f / DD, EPSV)));
        pak1[j] = make_float2(a1, __builtin_amdgcn_rsqf(fmaf(q1, 1.f / DD, EPSV)));
      }
    }
    __syncthreads();
    // j-loop: all from LDS, rs precomputed, no cross-lane ops
    for (int jj = wv; jj < 32; jj += 4) {
      const int jg = t0 + jj;
      const float2 ss = *(const float2*)(&st_[jj * 132 + 2 * lane]);
      const float sx0 = uu0.x + ss.x, sx1 = uu0.y + ss.y;
      const float tx0 = uu1.x + ss.x, tx1 = uu1.y + ss.y;
      if (jg != i0) {                    // wave-uniform
        const float2 p = pak0[jj];
        const float x0 = fmaf(p.x, wt2.x, sx0);
        const float x1 = fmaf(p.x, wt2.y, sx1);
        const float y0 = fmaf(x0 * p.y, g2.x, be2.x);
        const float y1 = fmaf(x1 * p.y, g2.y, be2.y);
        accA0 = fmaf(y0, __builtin_amdgcn_rcpf(1.f + __expf(-y0)), accA0);
        accA1 = fmaf(y1, __builtin_amdgcn_rcpf(1.f + __expf(-y1)), accA1);
      }
      if (jg != i1) {
        const float2 p = pak1[jj];
        const float x0 = fmaf(p.x, wt2.x, tx0);
        const float x1 = fmaf(p.x, wt2.y, tx1);
        const float y0 = fmaf(x0 * p.y, g2.x, be2.x);
        const float y1 = fmaf(x1 * p.y, g2.y, be2.y);
        accB0 = fmaf(y0, __builtin_amdgcn_rcpf(1.f + __expf(-y0)), accB0);
        accB1 = fmaf(y1, __builtin_amdgcn_rcpf(1.f + __expf(-y1)), accB1);
      }
    }
  }

  // reduce 4 waves -> agg rows (overlay in st_)
  __syncthreads();                       // all j-loops done reading st_
  *(float2*)(&st_[(wv * 2 + 0) * DD + 2 * lane]) = make_float2(accA0, accA1);
  *(float2*)(&st_[(wv * 2 + 1) * DD + 2 * lane]) = make_float2(accB0, accB1);
  __syncthreads();
  {
    const int ii = tid >> 7, e = tid & 127;
    st_[(8 + ii) * DD + e] = st_[(0 * 2 + ii) * DD + e] +
                             st_[(1 * 2 + ii) * DD + e] +
                             st_[(2 * 2 + ii) * DD + e] +
                             st_[(3 * 2 + ii) * DD + e];
  }
  __syncthreads();

  // upd tail: v[e] = bu[e] + h.Wu1 + agg.Wu2 (split halves), W streamed once
  const int half = tid >> 7, e = tid & 127;
  float v0 = (half == 0) ? bu[e] : 0.f;
  float v1 = v0;
  {
    const float* xin = (half == 0) ? hrow_ : &st_[8 * DD];
    const float* wcol = wut + (size_t)half * DD * DD + e;
#pragma unroll 8
    for (int k = 0; k < DD; ++k) {
      const float w = wcol[(size_t)k * DD];
      v0 = fmaf(xin[k], w, v0);
      v1 = fmaf(xin[DD + k], w, v1);
    }
  }
  if (half == 1) { upair_[e] = v0; upair_[DD + e] = v1; }  // comb (upair dead)
  __syncthreads();
  if (half == 0) {
    v0 += upair_[e];
    v1 += upair_[DD + e];
    const float sm0 = wave_reduce_add(v0), sq0 = wave_reduce_add(v0 * v0);
    const float sm1 = wave_reduce_add(v1), sq1 = wave_reduce_add(v1 * v1);
    if (lane == 0) {
      pm[wv][0] = sm0; pq[wv][0] = sq0;
      pm[wv][1] = sm1; pq[wv][1] = sq1;
    }
  }
  __syncthreads();
  if (half == 0) {
    const float ge = gu[e], bee = beu[e];
    {
      const float mean = (pm[0][0] + pm[1][0]) * (1.f / DD);
      const float var = (pq[0][0] + pq[1][0]) * (1.f / DD) - mean * mean;
      const float rs = __builtin_amdgcn_rsqf(var + EPSV);
      const float y = fmaf((v0 - mean) * rs, ge, bee);
      const float sg = __builtin_amdgcn_rcpf(1.f + __expf(-y));
      out[(size_t)(bNN + i0) * DD + e] = hrow_[e] + y * sg;
    }
    {
      const float mean = (pm[0][1] + pm[1][1]) * (1.f / DD);
      const float var = (pq[0][1] + pq[1][1]) * (1.f / DD) - mean * mean;
      const float rs = __builtin_amdgcn_rsqf(var + EPSV);
      const float y = fmaf((v1 - mean) * rs, ge, bee);
      const float sg = __builtin_amdgcn_rcpf(1.f + __expf(-y));
      out[(size_t)(bNN + i1) * DD + e] = hrow_[DD + e] + y * sg;
    }
  }
}

extern "C" void kernel_launch(void* const* d_in, const int* in_sizes, int n_in,
                              void* d_out, int out_size, void* d_ws, size_t ws_size,
                              hipStream_t stream) {
  const float* h    = (const float*)d_in[0];
  const float* adj  = (const float*)d_in[1];
  const float* Wm   = (const float*)d_in[2];
  const float* bmsg = (const float*)d_in[3];
  const float* gmsg = (const float*)d_in[4];
  const float* bemsg= (const float*)d_in[5];
  const float* Wu   = (const float*)d_in[6];
  const float* bupd = (const float*)d_in[7];
  const float* gupd = (const float*)d_in[8];
  const float* beupd= (const float*)d_in[9];
  float* out = (float*)d_out;

  float* ws    = (float*)d_ws;
  float* u     = ws;                        // 262144
  float* s     = u + BB * NN * DD;          // 262144
  float* rowA  = s + BB * NN * DD;          // 2048
  float* rowB  = rowA + BB * NN;            // 2048
  float* rowD2 = rowB + BB * NN;            // 2048
  float* rowE2 = rowD2 + BB * NN;           // 2048
  float* wtilv = rowE2 + BB * NN;           // 128
  float* wut   = wtilv + DD;                // 32768

  k_proj<<<512, 256, 0, stream>>>(h, Wm, bmsg, Wu, u, s, rowA, rowB, rowD2,
                                  rowE2, wtilv, wut);
  k_msgfused<<<1024, 256, 0, stream>>>(h, u, s, adj, rowA, rowB, rowD2, rowE2,
                                       wtilv, gmsg, bemsg, wut, bupd, gupd,
                                       beupd, out);
}